// Round 11
// baseline (166.649 us; speedup 1.0000x reference)
//
#include <hip/hip_runtime.h>
#include <hip/hip_bf16.h>

typedef __bf16 bf16x8 __attribute__((ext_vector_type(8)));
typedef __bf16 bf16x4 __attribute__((ext_vector_type(4)));
typedef float  f32x4  __attribute__((ext_vector_type(4)));

constexpr int kNHRZ = 2048, kBATCH = 128, kNU = 64, kNY = 64, kNH = 256, kH = 128;
constexpr int kCHUNK = 64, kNCHUNK = kNHRZ / kCHUNK;   // 32 chunks
constexpr int kTS = 16, kNSUB = kCHUNK / kTS;          // 4 subtiles of 16 t

// LDS strides (elements)
constexpr int U_STR = 72;    // bf16, 144 B rows (R9/R10 proven)
constexpr int X_STR = 268;   // bf16, 536 B rows (R6/R9 proven)
constexpr int UT_SZ = kTS * U_STR;                 // one 16-row U tile

constexpr int SMEM1  = 4 * UT_SZ * 2;              // pass1: 4 private tiles, 9216 B
constexpr int OFF_XS = 2 * UT_SZ * 2;              // pass2: shared U dbuf, 4608 B
constexpr int SMEM2  = OFF_XS + 2 * kTS * X_STR * 2;  // + Xs dbuf = 21760 B

__device__ inline bf16x8 pack8(float4 a, float4 b) {
    bf16x8 v;
    v[0] = (__bf16)a.x; v[1] = (__bf16)a.y; v[2] = (__bf16)a.z; v[3] = (__bf16)a.w;
    v[4] = (__bf16)b.x; v[5] = (__bf16)b.y; v[6] = (__bf16)b.z; v[7] = (__bf16)b.w;
    return v;
}

__device__ inline bf16x4 cvt4(float4 a) {
    bf16x4 v;
    v[0] = (__bf16)a.x; v[1] = (__bf16)a.y; v[2] = (__bf16)a.z; v[3] = (__bf16)a.w;
    return v;
}

// ---------------------------------------------------------------------------
// One batch per block (grid = 32 chunks x 128 batches = 4096), 4 waves.
// Slimmed for the 128-reg occupancy cliff (m68/m69): d-split GEMM1 (acc 8),
// Wf half-persistent (4 regs' worth reloaded per subtile from L1-hot W),
// l3/l8 recomputed. Target 4 waves/SIMD via __launch_bounds__(256,4) —
// safe now (R4's spill was forcing a ~160-reg kernel under the same bound).
// Pass1 (!FINAL): barrier-free, per-wave private U tile (in-place overwrite
//   guarded by lgkmcnt(0)+sched_barrier — rule #18).
// Pass2 (FINAL): shared U dbuf + Xs dbuf, ONE barrier per subtile.
// Wave w owns h-modes w*32+{0,16}+lw (d=0,1); MFMA 16x16x32:
//   A row=lane&15, k=(lane>>4)*8+j; C/D col=lane&15, row=(lane>>4)*4+i.
// Scan = R9-verified in-lane 4-step + shfl Kogge-Stone, per d-stream.
// ---------------------------------------------------------------------------
template <bool FINAL>
__global__ __launch_bounds__(256, 4) void scan_mfma(
    const float* __restrict__ U,      // (NHRZ, BATCH, NU)
    const float* __restrict__ lre,    // (H,)
    const float* __restrict__ lim,    // (H,)
    const float* __restrict__ Bmat,   // (NH, NU)
    const float* __restrict__ Wx2y,   // (NY, NH)   [FINAL]
    const float* __restrict__ bx2y,   // (NY,)      [FINAL]
    const float* __restrict__ starts, // (NCHUNK, BATCH, NH) [FINAL]
    float* __restrict__ ends,         // (NCHUNK, BATCH, NH) [!FINAL]
    float* __restrict__ out)          // (NHRZ+1, BATCH, NY) [FINAL]
{
    extern __shared__ char smem[];

    const int tid  = threadIdx.x;
    const int lane = tid & 63;
    const int w    = tid >> 6;        // wave 0..3
    const int lw   = lane & 15;
    const int lg   = lane >> 4;
    const int c    = blockIdx.x >> 7;         // chunk 0..31
    const int b    = blockIdx.x & 127;        // batch
    const int t0   = c * kCHUNK;

    __bf16* Up;                       // U tile base
    __bf16* Xs = nullptr;
    if constexpr (FINAL) {
        Up = (__bf16*)smem;                        // [2][kTS][U_STR] shared dbuf
        Xs = (__bf16*)(smem + OFF_XS);             // [2][kTS][X_STR]
    } else {
        Up = (__bf16*)smem + w * UT_SZ;            // private per-wave tile
    }

    // --- lambda constants l1,l2,l4 per d (l3,l8 recomputed on the fly)
    float l1r[2], l1i[2], l2r[2], l2i[2], l4r[2], l4i[2], nfv[2];
#pragma unroll
    for (int d = 0; d < 2; ++d) {
        const int hm = w * 32 + d * 16 + lw;
        const float ab = fabsf(lre[hm]);
        const float r  = expf(-ab);
        const float th = 1.5707963267948966f * lim[hm];
        l1r[d] = r * cosf(th);
        l1i[d] = r * sinf(th);
        l2r[d] = l1r[d]*l1r[d] - l1i[d]*l1i[d];
        l2i[d] = 2.0f * l1r[d] * l1i[d];
        l4r[d] = l2r[d]*l2r[d] - l2i[d]*l2i[d];
        l4i[d] = 2.0f * l2r[d] * l2i[d];
        nfv[d] = sqrtf(fmaxf(0.0f, 1.0f - expf(-2.0f * ab)));
    }

    // --- B fragments: Bf[ks][d]=real rows, Bf[ks][d+2]=imag rows (nf folded)
    bf16x8 Bf[2][4];
#pragma unroll
    for (int d = 0; d < 2; ++d) {
        const int hre = w * 32 + d * 16 + lw;
#pragma unroll
        for (int ks = 0; ks < 2; ++ks) {
            const float* p0 = Bmat + hre * kNU + ks * 32 + lg * 8;
            const float* p1 = Bmat + (hre + kH) * kNU + ks * 32 + lg * 8;
            float4 a0 = ((const float4*)p0)[0], a1 = ((const float4*)p0)[1];
            float4 b0 = ((const float4*)p1)[0], b1 = ((const float4*)p1)[1];
            const float nf = nfv[d];
            a0.x*=nf; a0.y*=nf; a0.z*=nf; a0.w*=nf;
            a1.x*=nf; a1.y*=nf; a1.z*=nf; a1.w*=nf;
            b0.x*=nf; b0.y*=nf; b0.z*=nf; b0.w*=nf;
            b1.x*=nf; b1.y*=nf; b1.z*=nf; b1.w*=nf;
            Bf[ks][d]     = pack8(a0, a1);
            Bf[ks][d + 2] = pack8(b0, b1);
        }
    }

    // --- W: wave's 16-y slice. ks 0..3 persistent regs; ks 4..7 reloaded
    // per subtile (same 16 B/lane every time -> L1-hot after first use).
    bf16x8 Wf[4];
    float bias = 0.f;
    const float* wrow = nullptr;
    if constexpr (FINAL) {
        const int y = w * 16 + lw;
        bias = bx2y[y];
        wrow = Wx2y + (size_t)y * kNH;
#pragma unroll
        for (int ks = 0; ks < 4; ++ks)
            Wf[ks] = pack8(((const float4*)(wrow + ks * 32 + lg * 8))[0],
                           ((const float4*)(wrow + ks * 32 + lg * 8))[1]);
    }

    // --- per-lane chunk-carry state (2 d-streams)
    float xr[2], xi[2];
#pragma unroll
    for (int d = 0; d < 2; ++d) {
        if constexpr (FINAL) {
            const int hm = w * 32 + d * 16 + lw;
            const size_t sb = ((size_t)c * kBATCH + b) * kNH;
            xr[d] = starts[sb + hm];
            xi[d] = starts[sb + hm + kH];
        } else {
            xr[d] = 0.0f; xi[d] = 0.0f;
        }
    }

    // --- prologue: stage subtile 0
    if constexpr (FINAL) {
        const int srow = tid >> 4, scol = tid & 15;
        float4 u = *(const float4*)(U + ((size_t)(t0 + srow) * kBATCH + b) * kNU + scol * 4);
        *(bf16x4*)&Up[srow * U_STR + scol * 4] = cvt4(u);
        __syncthreads();
    } else {
        float4 uld[4];
#pragma unroll
        for (int rep = 0; rep < 4; ++rep) {
            const int row = rep * 4 + lg;
            uld[rep] = *(const float4*)(U + ((size_t)(t0 + row) * kBATCH + b) * kNU + lw * 4);
        }
#pragma unroll
        for (int rep = 0; rep < 4; ++rep)
            *(bf16x4*)&Up[(rep * 4 + lg) * U_STR + lw * 4] = cvt4(uld[rep]);
        asm volatile("s_waitcnt lgkmcnt(0)" ::: "memory");
        __builtin_amdgcn_sched_barrier(0);
    }

#pragma unroll 1
    for (int s = 0; s < kNSUB; ++s) {
        __bf16* Uc = FINAL ? (Up + (s & 1) * UT_SZ) : Up;
        __bf16* Xc = nullptr;
        if constexpr (FINAL) Xc = Xs + (s & 1) * (kTS * X_STR);

        // ---- issue next-subtile global loads early
        float4 uld[FINAL ? 1 : 4];
        if (s + 1 < kNSUB) {
            if constexpr (FINAL) {
                const int srow = tid >> 4, scol = tid & 15;
                uld[0] = *(const float4*)(U +
                    ((size_t)(t0 + (s + 1) * kTS + srow) * kBATCH + b) * kNU + scol * 4);
            } else {
#pragma unroll
                for (int rep = 0; rep < 4; ++rep) {
                    const int row = rep * 4 + lg;
                    uld[rep] = *(const float4*)(U +
                        ((size_t)(t0 + (s + 1) * kTS + row) * kBATCH + b) * kNU + lw * 4);
                }
            }
        }

        // ---- A fragments (row = t_local = lw)
        bf16x8 A0 = *(const bf16x8*)&Uc[lw * U_STR + 0 * 32 + lg * 8];
        bf16x8 A1 = *(const bf16x8*)&Uc[lw * U_STR + 1 * 32 + lg * 8];

        // ---- per-d: GEMM1 (4 MFMA) + register scan + [FINAL] X writes
#pragma unroll
        for (int d = 0; d < 2; ++d) {
            f32x4 ar = {}, ai = {};
            ar = __builtin_amdgcn_mfma_f32_16x16x32_bf16(A0, Bf[0][d],     ar, 0, 0, 0);
            ai = __builtin_amdgcn_mfma_f32_16x16x32_bf16(A0, Bf[0][d + 2], ai, 0, 0, 0);
            ar = __builtin_amdgcn_mfma_f32_16x16x32_bf16(A1, Bf[1][d],     ar, 0, 0, 0);
            ai = __builtin_amdgcn_mfma_f32_16x16x32_bf16(A1, Bf[1][d + 2], ai, 0, 0, 0);

            float Lr[4], Li[4];
            Lr[0] = ar[0]; Li[0] = ai[0];
#pragma unroll
            for (int i = 1; i < 4; ++i) {
                Lr[i] = fmaf(l1r[d], Lr[i-1], fmaf(-l1i[d], Li[i-1], ar[i]));
                Li[i] = fmaf(l1i[d], Lr[i-1], fmaf( l1r[d], Li[i-1], ai[i]));
            }
            // inject carry at lg=0, shifted local ends elsewhere
            float vr = __shfl(Lr[3], (lane - 16) & 63);
            float vi = __shfl(Li[3], (lane - 16) & 63);
            float Tr = (lg == 0) ? xr[d] : vr;
            float Ti = (lg == 0) ? xi[d] : vi;
            // Kogge-Stone step 1 (factor l^4)
            float ur = __shfl(Tr, (lane - 16) & 63);
            float ui = __shfl(Ti, (lane - 16) & 63);
            float t1r = fmaf(l4r[d], ur, fmaf(-l4i[d], ui, Tr));
            float t1i = fmaf(l4i[d], ur, fmaf( l4r[d], ui, Ti));
            Tr = (lg >= 1) ? t1r : Tr;
            Ti = (lg >= 1) ? t1i : Ti;
            // step 2 (factor l^8, recomputed)
            const float l8r = l4r[d]*l4r[d] - l4i[d]*l4i[d];
            const float l8i = 2.0f * l4r[d] * l4i[d];
            ur = __shfl(Tr, (lane - 32) & 63);
            ui = __shfl(Ti, (lane - 32) & 63);
            t1r = fmaf(l8r, ur, fmaf(-l8i, ui, Tr));
            t1i = fmaf(l8i, ur, fmaf( l8r, ui, Ti));
            Tr = (lg >= 2) ? t1r : Tr;
            Ti = (lg >= 2) ? t1i : Ti;
            // chunk-carry: state after this lane-group, broadcast from lg=3
            const float spr = fmaf(l4r[d], Tr, fmaf(-l4i[d], Ti, Lr[3]));
            const float spi = fmaf(l4i[d], Tr, fmaf( l4r[d], Ti, Li[3]));
            xr[d] = __shfl(spr, lw | 48);
            xi[d] = __shfl(spi, lw | 48);

            if constexpr (FINAL) {
                const float l3r = l2r[d]*l1r[d] - l2i[d]*l1i[d];
                const float l3i = l2r[d]*l1i[d] + l2i[d]*l1r[d];
                const float pr[4] = {l1r[d], l2r[d], l3r, l4r[d]};
                const float pi[4] = {l1i[d], l2i[d], l3i, l4i[d]};
                const int hre = w * 32 + d * 16 + lw;
#pragma unroll
                for (int i = 0; i < 4; ++i) {
                    const float xtr = fmaf(pr[i], Tr, fmaf(-pi[i], Ti, Lr[i]));
                    const float xti = fmaf(pi[i], Tr, fmaf( pr[i], Ti, Li[i]));
                    const int m = lg * 4 + i;
                    Xc[m * X_STR + hre]      = (__bf16)xtr;
                    Xc[m * X_STR + hre + kH] = (__bf16)xti;
                }
            }
        }

        if constexpr (FINAL) {
            // stage next subtile into the other shared buffer
            if (s + 1 < kNSUB) {
                const int srow = tid >> 4, scol = tid & 15;
                *(bf16x4*)&Up[((s + 1) & 1) * UT_SZ + srow * U_STR + scol * 4] = cvt4(uld[0]);
            }
            __syncthreads();  // Xs[cur] + Up[next] ready (WAR audited: dbuf)
            // ---- GEMM2: M=16 t x N=16 y (this wave's slice), K=256
            f32x4 acc2 = {};
#pragma unroll
            for (int ks = 0; ks < 4; ++ks) {
                bf16x8 a = *(const bf16x8*)&Xc[lw * X_STR + ks * 32 + lg * 8];
                acc2 = __builtin_amdgcn_mfma_f32_16x16x32_bf16(a, Wf[ks], acc2, 0, 0, 0);
            }
#pragma unroll
            for (int ks = 4; ks < 8; ++ks) {
                bf16x8 a  = *(const bf16x8*)&Xc[lw * X_STR + ks * 32 + lg * 8];
                bf16x8 wk = pack8(((const float4*)(wrow + ks * 32 + lg * 8))[0],
                                  ((const float4*)(wrow + ks * 32 + lg * 8))[1]);
                acc2 = __builtin_amdgcn_mfma_f32_16x16x32_bf16(a, wk, acc2, 0, 0, 0);
            }
#pragma unroll
            for (int i = 0; i < 4; ++i) {
                const int t = t0 + s * kTS + lg * 4 + i;
                out[((size_t)(1 + t) * kBATCH + b) * kNY + w * 16 + lw] = acc2[i] + bias;
            }
        } else {
            // in-place overwrite of the private tile (guard per rule #18)
            asm volatile("s_waitcnt lgkmcnt(0)" ::: "memory");
            __builtin_amdgcn_sched_barrier(0);
            if (s + 1 < kNSUB) {
#pragma unroll
                for (int rep = 0; rep < 4; ++rep)
                    *(bf16x4*)&Up[(rep * 4 + lg) * U_STR + lw * 4] = cvt4(uld[rep]);
            }
        }
    }

    if constexpr (!FINAL) {
#pragma unroll
        for (int d = 0; d < 2; ++d) {
            const int hm = w * 32 + d * 16 + lw;
            const size_t eb = ((size_t)c * kBATCH + b) * kNH;
            ends[eb + hm]      = xr[d];
            ends[eb + hm + kH] = xi[d];
        }
    }
}

// ---------------------------------------------------------------------------
// Sequential combine over chunks + x0 computation.
// ---------------------------------------------------------------------------
__global__ __launch_bounds__(128) void combine_kernel(
    const float* __restrict__ y0, const float* __restrict__ Wy2x,
    const float* __restrict__ by2x, const float* __restrict__ lre,
    const float* __restrict__ lim, const float* __restrict__ ends,
    float* __restrict__ starts)
{
    const int b  = blockIdx.x;
    const int hm = threadIdx.x;

    const float ab = fabsf(lre[hm]);
    const float r  = expf(-ab);
    const float th = 1.5707963267948966f * lim[hm];
    float lr = r * cosf(th);
    float li = r * sinf(th);
    float pr = lr, pi = li;
#pragma unroll
    for (int k = 0; k < 6; ++k) {  // lambda^64
        const float nr = pr * pr - pi * pi;
        const float ni = 2.0f * pr * pi;
        pr = nr; pi = ni;
    }

    float s1 = by2x[hm];
    float s2 = by2x[hm + kH];
#pragma unroll 8
    for (int q = 0; q < kNY; ++q) {
        const float yv = y0[b * kNY + q];
        s1 = fmaf(Wy2x[hm * kNY + q], yv, s1);
        s2 = fmaf(Wy2x[(hm + kH) * kNY + q], yv, s2);
    }

    for (int c = 0; c < kNCHUNK; ++c) {
        const size_t base = ((size_t)c * kBATCH + b) * kNH;
        starts[base + hm]      = s1;
        starts[base + hm + kH] = s2;
        const float e1 = ends[base + hm];
        const float e2 = ends[base + hm + kH];
        const float n1 = fmaf(pr, s1, fmaf(-pi, s2, e1));
        const float n2 = fmaf(pi, s1, fmaf(pr, s2, e2));
        s1 = n1; s2 = n2;
    }
}

// Y row 0 = Wx2y @ x0 + bx2y  (x0 = starts[c=0])
__global__ __launch_bounds__(64) void y0_kernel(
    const float* __restrict__ starts, const float* __restrict__ Wx2y,
    const float* __restrict__ bx2y, float* __restrict__ out)
{
    const int b = blockIdx.x;
    const int y = threadIdx.x;
    const float* x0 = starts + (size_t)b * kNH;
    float acc = bx2y[y];
#pragma unroll 4
    for (int h = 0; h < kNH; h += 4) {
        float4 xv = *(const float4*)&x0[h];
        float4 wv = *(const float4*)&Wx2y[y * kNH + h];
        acc = fmaf(wv.x, xv.x, acc);
        acc = fmaf(wv.y, xv.y, acc);
        acc = fmaf(wv.z, xv.z, acc);
        acc = fmaf(wv.w, xv.w, acc);
    }
    out[(size_t)b * kNY + y] = acc;
}

extern "C" void kernel_launch(void* const* d_in, const int* in_sizes, int n_in,
                              void* d_out, int out_size, void* d_ws, size_t ws_size,
                              hipStream_t stream) {
    const float* y0   = (const float*)d_in[0];
    const float* U    = (const float*)d_in[1];
    const float* lre  = (const float*)d_in[2];
    const float* lim  = (const float*)d_in[3];
    const float* Bmat = (const float*)d_in[4];
    const float* Wy2x = (const float*)d_in[5];
    const float* by2x = (const float*)d_in[6];
    const float* Wx2y = (const float*)d_in[7];
    const float* bx2y = (const float*)d_in[8];
    float* out = (float*)d_out;

    float* ends   = (float*)d_ws;                          // 4 MB
    float* starts = ends + (size_t)kNCHUNK * kBATCH * kNH; // 4 MB

    const int grid = kNCHUNK * kBATCH;  // 4096 blocks, one batch each

    scan_mfma<false><<<grid, 256, SMEM1, stream>>>(
        U, lre, lim, Bmat, nullptr, nullptr, nullptr, ends, nullptr);
    combine_kernel<<<kBATCH, 128, 0, stream>>>(
        y0, Wy2x, by2x, lre, lim, ends, starts);
    y0_kernel<<<kBATCH, 64, 0, stream>>>(starts, Wx2y, bx2y, out);
    scan_mfma<true><<<grid, 256, SMEM2, stream>>>(
        U, lre, lim, Bmat, Wx2y, bx2y, starts, nullptr, out);
}

// Round 12
// 91.813 us; speedup vs baseline: 1.8151x; 1.8151x over previous
//
#include <hip/hip_runtime.h>
#include <hip/hip_bf16.h>

typedef __bf16 bf16x8 __attribute__((ext_vector_type(8)));
typedef float  f32x4  __attribute__((ext_vector_type(4)));

constexpr int kNHRZ = 2048, kBATCH = 128, kNU = 64, kNY = 64, kNH = 256, kH = 128;
constexpr int kCHUNK = 256, kNCHUNK = kNHRZ / kCHUNK;  // 8 chunks of 256 steps
constexpr int kTS = 16, kBT = 2, kM = kTS * kBT;       // 32 (t,b) rows per subtile
constexpr int kNSUB = kCHUNK / kTS;                    // 16 subtiles per chunk

// LDS strides (elements) — R2/R5-proven
constexpr int U_STR  = 72;   // bf16, 144 B rows
constexpr int BU_STR = 272;  // bf16, 544 B rows; 544 % 128 == 32 -> 4 GEMM1 store
                             // rows (lg) hit disjoint 8-bank groups (conflict-free)
constexpr int X_STR  = 264;  // bf16, 528 B rows

constexpr int OFF_U  = 0;
constexpr int OFF_BU = OFF_U + kM * U_STR * 2;     // 4608
constexpr int OFF_X  = OFF_BU + kM * BU_STR * 2;   // 22016
constexpr int SMEM1  = OFF_X;                      // pass1: 22016 B
constexpr int SMEM2  = OFF_X + kM * X_STR * 2;     // pass2: 38912 B

__device__ inline bf16x8 pack8(float4 a, float4 b) {
    bf16x8 v;
    v[0] = (__bf16)a.x; v[1] = (__bf16)a.y; v[2] = (__bf16)a.z; v[3] = (__bf16)a.w;
    v[4] = (__bf16)b.x; v[5] = (__bf16)b.y; v[6] = (__bf16)b.z; v[7] = (__bf16)b.w;
    return v;
}

// ---------------------------------------------------------------------------
// Fused per-chunk kernel (R5-verified body; only the chunk length changed).
// Block = (chunk c, batch pair), 256 threads = 4 waves, 16 subtiles/block.
// Grid = 8 x 64 = 512 blocks = exactly 2 blocks/CU resident — one residency
// round; per-block preamble (transcendentals + B/W fragment gathers, (w,lane)-
// dependent only) amortized over 4x more work than R2/R5.
// MFMA 16x16x32 bf16 layouts (gfx950):
//   A: row = lane&15, k = (lane>>4)*8 + j
//   B: col = lane&15, k = (lane>>4)*8 + j
//   C/D: col = lane&15, row = (lane>>4)*4 + i
// NOTE: __launch_bounds__(256,2) — NOT (256,4): tighter bound spills the
// fragment arrays (R4: VGPR 116->64, +950MB scratch; R11 same at 64 VGPR).
// ---------------------------------------------------------------------------
template <bool FINAL>
__global__ __launch_bounds__(256, 2) void scan_mfma(
    const float* __restrict__ U,      // (NHRZ, BATCH, NU)
    const float* __restrict__ lre,    // (H,)
    const float* __restrict__ lim,    // (H,)
    const float* __restrict__ Bmat,   // (NH, NU)
    const float* __restrict__ Wx2y,   // (NY, NH)   [FINAL]
    const float* __restrict__ bx2y,   // (NY,)      [FINAL]
    const float* __restrict__ starts, // (NCHUNK, BATCH, NH) [FINAL]
    float* __restrict__ ends,         // (NCHUNK, BATCH, NH) [!FINAL]
    float* __restrict__ out)          // (NHRZ+1, BATCH, NY) [FINAL]
{
    extern __shared__ char smem[];
    __bf16* Us = (__bf16*)(smem + OFF_U);    // [kM][U_STR]
    __bf16* Bu = (__bf16*)(smem + OFF_BU);   // [kM][BU_STR]
    __bf16* Xs = (__bf16*)(smem + OFF_X);    // [kM][X_STR]  (FINAL)

    const int tid  = threadIdx.x;
    const int lane = tid & 63;
    const int w    = tid >> 6;            // wave 0..3
    const int lw   = lane & 15;
    const int lg   = lane >> 4;
    const int blk  = blockIdx.x;
    const int c    = blk >> 6;            // chunk 0..7
    const int bp   = blk & 63;            // batch pair 0..63
    const int bglob = bp * 2;
    const int t0   = c * kCHUNK;

    // --- B fragments in registers: wave w owns h-cols [w*64, w*64+64), nf folded
    bf16x8 Bf[2][4];  // [ks][nt]
#pragma unroll
    for (int nt = 0; nt < 4; ++nt) {
        const int h  = w * 64 + nt * 16 + lw;
        const float ab = fabsf(lre[h & (kH - 1)]);
        const float nf = sqrtf(fmaxf(0.0f, 1.0f - expf(-2.0f * ab)));
#pragma unroll
        for (int ks = 0; ks < 2; ++ks) {
            const float* p = Bmat + h * kNU + ks * 32 + lg * 8;
            float4 f0 = ((const float4*)p)[0];
            float4 f1 = ((const float4*)p)[1];
            f0.x *= nf; f0.y *= nf; f0.z *= nf; f0.w *= nf;
            f1.x *= nf; f1.y *= nf; f1.z *= nf; f1.w *= nf;
            Bf[ks][nt] = pack8(f0, f1);
        }
    }

    // --- W fragments + bias in registers (FINAL)
    bf16x8 Wf[8][2];
    float  bias[2] = {0.f, 0.f};
    if constexpr (FINAL) {
#pragma unroll
        for (int nt = 0; nt < 2; ++nt) {
            const int y = (w >> 1) * 32 + nt * 16 + lw;
            bias[nt] = bx2y[y];
#pragma unroll
            for (int ks = 0; ks < 8; ++ks) {
                const float* p = Wx2y + y * kNH + ks * 32 + lg * 8;
                Wf[ks][nt] = pack8(((const float4*)p)[0], ((const float4*)p)[1]);
            }
        }
    }

    // --- per-thread scan constants / state: thread = (hm, bl)
    const int hm = tid & 127;
    const int bl = tid >> 7;
    float lr, li;
    {
        const float ab = fabsf(lre[hm]);
        const float r  = expf(-ab);
        const float th = 1.5707963267948966f * lim[hm];
        lr = r * cosf(th);
        li = r * sinf(th);
    }
    float x1, x2;
    if constexpr (FINAL) {
        const size_t sb = ((size_t)c * kBATCH + bglob + bl) * kNH;
        x1 = starts[sb + hm];
        x2 = starts[sb + hm + kH];
    } else {
        x1 = 0.0f; x2 = 0.0f;
    }

    // U staging map: thread -> (m = tid>>3, q = tid&7), 32 B of U per thread
    const int sm = tid >> 3, sq = tid & 7;
    const float* uptr0 =
        U + ((size_t)(t0 + (sm >> 1)) * kBATCH + (bglob + (sm & 1))) * kNU + sq * 8;

    // prefetch subtile 0
    float4 u0 = ((const float4*)uptr0)[0];
    float4 u1 = ((const float4*)uptr0)[1];

#pragma unroll 1
    for (int s = 0; s < kNSUB; ++s) {
        // ---- write staged U regs -> LDS, then issue next prefetch
        *(bf16x8*)&Us[sm * U_STR + sq * 8] = pack8(u0, u1);
        if (s + 1 < kNSUB) {
            const float* p = uptr0 + (size_t)(s + 1) * kTS * kBATCH * kNU;
            u0 = ((const float4*)p)[0];
            u1 = ((const float4*)p)[1];
        }
        __syncthreads();  // B: U staged (also: prev scan's Bu reads done)

        // ---- GEMM1: Bu[m][h] (M=32, N=256/4 waves, K=64), output bf16
        {
            f32x4 acc[2][4] = {};
#pragma unroll
            for (int ks = 0; ks < 2; ++ks) {
                bf16x8 a0 = *(const bf16x8*)&Us[(lw)      * U_STR + ks * 32 + lg * 8];
                bf16x8 a1 = *(const bf16x8*)&Us[(16 + lw) * U_STR + ks * 32 + lg * 8];
#pragma unroll
                for (int nt = 0; nt < 4; ++nt) {
                    acc[0][nt] = __builtin_amdgcn_mfma_f32_16x16x32_bf16(a0, Bf[ks][nt], acc[0][nt], 0, 0, 0);
                    acc[1][nt] = __builtin_amdgcn_mfma_f32_16x16x32_bf16(a1, Bf[ks][nt], acc[1][nt], 0, 0, 0);
                }
            }
#pragma unroll
            for (int mt = 0; mt < 2; ++mt)
#pragma unroll
                for (int nt = 0; nt < 4; ++nt)
#pragma unroll
                    for (int i = 0; i < 4; ++i)
                        Bu[(mt * 16 + lg * 4 + i) * BU_STR + w * 64 + nt * 16 + lw] =
                            (__bf16)acc[mt][nt][i];
        }
        __syncthreads();  // C: Bu ready (also: prev GEMM2's X reads done)

        // ---- register scan, 16 steps
#pragma unroll
        for (int t = 0; t < kTS; ++t) {
            const int m = t * kBT + bl;
            const float bu1 = (float)Bu[m * BU_STR + hm];
            const float bu2 = (float)Bu[m * BU_STR + kH + hm];
            const float n1 = fmaf(lr, x1, fmaf(-li, x2, bu1));
            const float n2 = fmaf(li, x1, fmaf(lr, x2, bu2));
            x1 = n1; x2 = n2;
            if constexpr (FINAL) {
                Xs[m * X_STR + hm]      = (__bf16)x1;
                Xs[m * X_STR + kH + hm] = (__bf16)x2;
            }
        }

        if constexpr (FINAL) {
            __syncthreads();  // D: X ready
            // ---- Y GEMM: M=32 (mt=w&1), N=32 (y base (w>>1)*32), K=256
            f32x4 acc[2] = {};
            const int mt = w & 1;
#pragma unroll
            for (int ks = 0; ks < 8; ++ks) {
                bf16x8 a = *(const bf16x8*)&Xs[(mt * 16 + lw) * X_STR + ks * 32 + lg * 8];
                acc[0] = __builtin_amdgcn_mfma_f32_16x16x32_bf16(a, Wf[ks][0], acc[0], 0, 0, 0);
                acc[1] = __builtin_amdgcn_mfma_f32_16x16x32_bf16(a, Wf[ks][1], acc[1], 0, 0, 0);
            }
            // ---- direct store from acc (+bias): 4x64B segments per instr
#pragma unroll
            for (int i = 0; i < 4; ++i) {
                const int m = mt * 16 + lg * 4 + i;
                const int t = t0 + s * kTS + (m >> 1);
                const int b = bglob + (m & 1);
                float* orow = out + ((size_t)(1 + t) * kBATCH + b) * kNY + (w >> 1) * 32 + lw;
#pragma unroll
                for (int nt = 0; nt < 2; ++nt)
                    orow[nt * 16] = acc[nt][i] + bias[nt];
            }
        }
    }

    if constexpr (!FINAL) {
        const size_t eb = ((size_t)c * kBATCH + bglob + bl) * kNH;
        ends[eb + hm]      = x1;
        ends[eb + hm + kH] = x2;
    }
}

// ---------------------------------------------------------------------------
// Sequential combine over chunks + x0 computation. lambda^256 = 8 squarings.
// ---------------------------------------------------------------------------
__global__ __launch_bounds__(128) void combine_kernel(
    const float* __restrict__ y0, const float* __restrict__ Wy2x,
    const float* __restrict__ by2x, const float* __restrict__ lre,
    const float* __restrict__ lim, const float* __restrict__ ends,
    float* __restrict__ starts)
{
    const int b  = blockIdx.x;
    const int hm = threadIdx.x;

    const float ab = fabsf(lre[hm]);
    const float r  = expf(-ab);
    const float th = 1.5707963267948966f * lim[hm];
    float lr = r * cosf(th);
    float li = r * sinf(th);
    float pr = lr, pi = li;
#pragma unroll
    for (int k = 0; k < 8; ++k) {  // lambda^256 (kCHUNK = 256 = 2^8)
        const float nr = pr * pr - pi * pi;
        const float ni = 2.0f * pr * pi;
        pr = nr; pi = ni;
    }

    float s1 = by2x[hm];
    float s2 = by2x[hm + kH];
#pragma unroll 8
    for (int q = 0; q < kNY; ++q) {
        const float yv = y0[b * kNY + q];
        s1 = fmaf(Wy2x[hm * kNY + q], yv, s1);
        s2 = fmaf(Wy2x[(hm + kH) * kNY + q], yv, s2);
    }

    for (int c = 0; c < kNCHUNK; ++c) {
        const size_t base = ((size_t)c * kBATCH + b) * kNH;
        starts[base + hm]      = s1;
        starts[base + hm + kH] = s2;
        const float e1 = ends[base + hm];
        const float e2 = ends[base + hm + kH];
        const float n1 = fmaf(pr, s1, fmaf(-pi, s2, e1));
        const float n2 = fmaf(pi, s1, fmaf(pr, s2, e2));
        s1 = n1; s2 = n2;
    }
}

// Y row 0 = Wx2y @ x0 + bx2y  (x0 = starts[c=0])
__global__ __launch_bounds__(64) void y0_kernel(
    const float* __restrict__ starts, const float* __restrict__ Wx2y,
    const float* __restrict__ bx2y, float* __restrict__ out)
{
    const int b = blockIdx.x;
    const int y = threadIdx.x;
    const float* x0 = starts + (size_t)b * kNH;
    float acc = bx2y[y];
#pragma unroll 4
    for (int h = 0; h < kNH; h += 4) {
        float4 xv = *(const float4*)&x0[h];
        float4 wv = *(const float4*)&Wx2y[y * kNH + h];
        acc = fmaf(wv.x, xv.x, acc);
        acc = fmaf(wv.y, xv.y, acc);
        acc = fmaf(wv.z, xv.z, acc);
        acc = fmaf(wv.w, xv.w, acc);
    }
    out[(size_t)b * kNY + y] = acc;
}

extern "C" void kernel_launch(void* const* d_in, const int* in_sizes, int n_in,
                              void* d_out, int out_size, void* d_ws, size_t ws_size,
                              hipStream_t stream) {
    const float* y0   = (const float*)d_in[0];
    const float* U    = (const float*)d_in[1];
    const float* lre  = (const float*)d_in[2];
    const float* lim  = (const float*)d_in[3];
    const float* Bmat = (const float*)d_in[4];
    const float* Wy2x = (const float*)d_in[5];
    const float* by2x = (const float*)d_in[6];
    const float* Wx2y = (const float*)d_in[7];
    const float* bx2y = (const float*)d_in[8];
    float* out = (float*)d_out;

    float* ends   = (float*)d_ws;                          // 1 MB
    float* starts = ends + (size_t)kNCHUNK * kBATCH * kNH; // 1 MB

    const int grid = kNCHUNK * (kBATCH / kBT);  // 512 blocks = 2/CU resident

    scan_mfma<false><<<grid, 256, SMEM1, stream>>>(
        U, lre, lim, Bmat, nullptr, nullptr, nullptr, ends, nullptr);
    combine_kernel<<<kBATCH, 128, 0, stream>>>(
        y0, Wy2x, by2x, lre, lim, ends, starts);
    y0_kernel<<<kBATCH, 64, 0, stream>>>(starts, Wx2y, bx2y, out);
    scan_mfma<true><<<grid, 256, SMEM2, stream>>>(
        U, lre, lim, Bmat, Wx2y, bx2y, starts, nullptr, out);
}